// Round 3
// baseline (237.551 us; speedup 1.0000x reference)
//
#include <hip/hip_runtime.h>

// IDWT reconstruction layer, register p-tiled, PT=8.
// x: (B=16, L=32768, 64) f32, channels [0,32)=approx, [32,64)=detail.
// out: (16, 2L=65536, 32) f32.
//
// out[b, 2p,   c] = sum_t lo[2t+1]*A[p-1+t] + hi[2t+1]*D[p-1+t]
// out[b, 2p+1, c] = sum_t lo[2t  ]*A[p-1+t] + hi[2t  ]*D[p-1+t]
// (t in 0..3; rows outside [0,L) contribute zero)
//
// PT=8: each thread covers 8 consecutive p for one 4-channel group.
// Loads rows p0-1 .. p0+9 (11 rows) once: 22 loads + 16 stores per
// 8 p-pairs (4.75 VMEM/p vs 10 in the naive version). Read
// amplification at L1/L2: 11/8 = 1.375x (naive: 4x).

#define B_    16
#define L_    32768
#define CIN_  64
#define COUT_ 32
#define PT    8
#define NROW  (PT + 3)   // 11

// native vector type for nontemporal builtins (HIP float4 is a struct)
typedef float vfloat4 __attribute__((ext_vector_type(4)));

__global__ __launch_bounds__(256) void idwt_kernel(
    const float* __restrict__ x,
    const float* __restrict__ rec_lo,
    const float* __restrict__ rec_hi,
    float* __restrict__ out)
{
    const int tid = blockIdx.x * blockDim.x + threadIdx.x;
    const int g  = tid & 7;                   // channel group of 4 (c = 4g)
    const int pp = tid >> 3;                  // (b, p0/PT) combined
    const int p0 = (pp & (L_ / PT - 1)) * PT;
    const int b  = pp >> 12;                  // L_/PT = 4096 = 2^12

    const float* xb = x + b * (L_ * CIN_) + (g << 2);

    // Stage 11 rows (A and D halves) in registers.
    float A[NROW][4], D[NROW][4];
#pragma unroll
    for (int r = 0; r < NROW; ++r) {
        const int j = p0 - 1 + r;
        if (j >= 0 && j < L_) {               // false only at batch edges
            const vfloat4 a = *(const vfloat4*)(xb + j * CIN_);
            const vfloat4 d = *(const vfloat4*)(xb + j * CIN_ + COUT_);
            A[r][0] = a.x; A[r][1] = a.y; A[r][2] = a.z; A[r][3] = a.w;
            D[r][0] = d.x; D[r][1] = d.y; D[r][2] = d.z; D[r][3] = d.w;
        } else {
#pragma unroll
            for (int c = 0; c < 4; ++c) { A[r][c] = 0.f; D[r][c] = 0.f; }
        }
    }

    // wave-uniform filter loads (compiler scalarizes to s_load)
    float lo[8], hi[8];
#pragma unroll
    for (int k = 0; k < 8; ++k) { lo[k] = rec_lo[k]; hi[k] = rec_hi[k]; }

    float* ob = out + (b * (2 * L_) + 2 * p0) * COUT_ + (g << 2);

#pragma unroll
    for (int pi = 0; pi < PT; ++pi) {
        float ev[4], od[4];
#pragma unroll
        for (int c = 0; c < 4; ++c) {
            float e = 0.f, o = 0.f;
#pragma unroll
            for (int t = 0; t < 4; ++t) {
                const float a = A[pi + t][c];
                const float d = D[pi + t][c];
                e = fmaf(lo[2 * t + 1], a, e);
                e = fmaf(hi[2 * t + 1], d, e);
                o = fmaf(lo[2 * t],     a, o);
                o = fmaf(hi[2 * t],     d, o);
            }
            ev[c] = e; od[c] = o;
        }
        // Output never re-read: nontemporal stores keep L2/LLC for input.
        vfloat4* pe = (vfloat4*)(ob + (2 * pi)     * COUT_);
        vfloat4* po = (vfloat4*)(ob + (2 * pi + 1) * COUT_);
        vfloat4 ve = { ev[0], ev[1], ev[2], ev[3] };
        vfloat4 vo = { od[0], od[1], od[2], od[3] };
        __builtin_nontemporal_store(ve, pe);
        __builtin_nontemporal_store(vo, po);
    }
}

extern "C" void kernel_launch(void* const* d_in, const int* in_sizes, int n_in,
                              void* d_out, int out_size, void* d_ws, size_t ws_size,
                              hipStream_t stream) {
    const float* x      = (const float*)d_in[0];
    const float* rec_lo = (const float*)d_in[1];
    const float* rec_hi = (const float*)d_in[2];
    float* out = (float*)d_out;

    const int total_threads = B_ * (L_ / PT) * (COUT_ / 4); // 16*4096*8 = 524,288
    const int block = 256;
    idwt_kernel<<<total_threads / block, block, 0, stream>>>(x, rec_lo, rec_hi, out);
}

// Round 4
// 226.865 us; speedup vs baseline: 1.0471x; 1.0471x over previous
//
#include <hip/hip_runtime.h>

// IDWT reconstruction, parity-split lanes + A/D lane-split loads.
// x: (B=16, L=32768, 64) f32, channels [0,32)=approx A, [32,64)=detail D.
// out: (16, 2L, 32) f32.
//
// out[b, 2p,   c] = sum_t lo[2t+1]*A[p-1+t][c] + hi[2t+1]*D[p-1+t][c]
// out[b, 2p+1, c] = sum_t lo[2t  ]*A[p-1+t][c] + hi[2t  ]*D[p-1+t][c]
//
// Thread = (b, p, parity, c4). parity 0 -> even row, loads A-half only;
// parity 1 -> odd row, loads D-half only. Halves exchanged via
// __shfl_xor(lane^8). Wave-level loads AND stores are fully dense 1 KB
// (lanes 0-7 = A chunk, 8-15 = adjacent D chunk, 16-31 = next row...).
// 5 VMEM / thread; 8.4M threads = 32768 WGs for max TLP (kernel is
// latency-bound: VALUBusy 4%, HBM 30%, occupancy 33% at PT=8).

#define B_    16
#define L_    32768
#define CIN_  64
#define COUT_ 32

typedef float vfloat4 __attribute__((ext_vector_type(4)));

__global__ __launch_bounds__(256) void idwt_kernel(
    const float* __restrict__ x,
    const float* __restrict__ rec_lo,
    const float* __restrict__ rec_hi,
    float* __restrict__ out)
{
    const int tid    = blockIdx.x * blockDim.x + threadIdx.x;
    const int g      = tid & 7;          // float4 channel group
    const int parity = (tid >> 3) & 1;   // 0: even output row, 1: odd
    const int pp     = tid >> 4;         // (b, p)
    const int p      = pp & (L_ - 1);
    const int b      = pp >> 15;         // L_ = 2^15

    // my half: parity 0 -> A at +0, parity 1 -> D at +32 floats
    const float* xb = x + b * (L_ * CIN_) + (g << 2) + (parity ? COUT_ : 0);

    // Load my 4 rows (16 floats). Wave: fully dense 1KB per load instr.
    float m[4][4];
#pragma unroll
    for (int t = 0; t < 4; ++t) {
        const int j = p - 1 + t;
        if ((unsigned)j < (unsigned)L_) {
            const vfloat4 v = *(const vfloat4*)(xb + j * CIN_);
            m[t][0] = v.x; m[t][1] = v.y; m[t][2] = v.z; m[t][3] = v.w;
        } else {
            m[t][0] = 0.f; m[t][1] = 0.f; m[t][2] = 0.f; m[t][3] = 0.f;
        }
    }

    // Exchange halves with the partner lane (lane ^ 8): I get the other
    // half's 16 floats. VALU/LDS pipes are idle; this is free.
    float o_[4][4];
#pragma unroll
    for (int t = 0; t < 4; ++t)
#pragma unroll
        for (int c = 0; c < 4; ++c)
            o_[t][c] = __shfl_xor(m[t][c], 8, 64);

    // Filter coefficients applied to my-loaded half (fm) and received
    // half (fo):
    //   parity 0: m=A -> fm[t]=lo[2t+1], o_=D -> fo[t]=hi[2t+1]
    //   parity 1: m=D -> fm[t]=hi[2t],   o_=A -> fo[t]=lo[2t]
    float fm[4], fo[4];
#pragma unroll
    for (int t = 0; t < 4; ++t) {
        fm[t] = parity ? rec_hi[2 * t]     : rec_lo[2 * t + 1];
        fo[t] = parity ? rec_lo[2 * t]     : rec_hi[2 * t + 1];
    }

    float acc[4] = {0.f, 0.f, 0.f, 0.f};
#pragma unroll
    for (int t = 0; t < 4; ++t)
#pragma unroll
        for (int c = 0; c < 4; ++c)
            acc[c] = fmaf(fm[t], m[t][c], fmaf(fo[t], o_[t][c], acc[c]));

    // Store one float4. Wave: fully dense 1KB (g fastest, then parity
    // = adjacent row, then p = next row-pair).
    float* orow = out + (b * (2 * L_) + 2 * p + parity) * COUT_ + (g << 2);
    vfloat4 v = { acc[0], acc[1], acc[2], acc[3] };
    __builtin_nontemporal_store(v, (vfloat4*)orow);
}

extern "C" void kernel_launch(void* const* d_in, const int* in_sizes, int n_in,
                              void* d_out, int out_size, void* d_ws, size_t ws_size,
                              hipStream_t stream) {
    const float* x      = (const float*)d_in[0];
    const float* rec_lo = (const float*)d_in[1];
    const float* rec_hi = (const float*)d_in[2];
    float* out = (float*)d_out;

    const int total_threads = B_ * L_ * 2 * (COUT_ / 4); // 8,388,608
    const int block = 256;
    idwt_kernel<<<total_threads / block, block, 0, stream>>>(x, rec_lo, rec_hi, out);
}